// Round 12
// baseline (98.917 us; speedup 1.0000x reference)
//
#include <hip/hip_runtime.h>

#define T_SEQ 4096
#define NBATCH 2
#define DM 1024
#define DI 32
#define NH 4
#define NCOLS 164      // 128 q + 32 k + 4 w
#define NCOLS_PAD 192  // 12 tiles of 16
#define KC 64          // K-chunk for proj v2
#define BSTRIDE 72     // shorts per col-slice in LDS (64 + 8 pad)

typedef __attribute__((ext_vector_type(8))) short bf16x8;
typedef __attribute__((ext_vector_type(4))) float f32x4;

__device__ __forceinline__ unsigned short f2bf(float f) {
    unsigned int u = __builtin_bit_cast(unsigned int, f);
    u += 0x7FFFu + ((u >> 16) & 1u);   // RNE; inputs have no NaN
    return (unsigned short)(u >> 16);
}

// ---------------- prep: W^T -> bf16 [192][1024], bias[192] ----------------
__global__ __launch_bounds__(256) void prep_kernel(
    const float* __restrict__ Wq, const float* __restrict__ bq,
    const float* __restrict__ Wk, const float* __restrict__ bk,
    const float* __restrict__ Ww, const float* __restrict__ bw,
    unsigned short* __restrict__ WT, float* __restrict__ bias) {
    int c = blockIdx.x;                    // 0..191
    const float* src = nullptr; int stride = 0; float bv = 0.f;
    if (c < 128)      { src = Wq + c;       stride = NH * DI; bv = bq[c]; }
    else if (c < 160) { src = Wk + (c-128); stride = DI;      bv = bk[c-128]; }
    else if (c < 164) { src = Ww + (c-160); stride = NH;      bv = bw[c-160]; }
    for (int k = threadIdx.x; k < DM; k += blockDim.x) {
        float v = src ? src[(size_t)k * stride] : 0.f;
        WT[(size_t)c * DM + k] = f2bf(v);
    }
    if (threadIdx.x == 0) bias[c] = bv;
}

// ---------------- projection v2: LDS-staged, double-buffered (R9, best) ----------------
__global__ __launch_bounds__(256) void proj_kernel(
    const float* __restrict__ x, const unsigned short* __restrict__ WT,
    const float* __restrict__ bias,
    unsigned short* __restrict__ qws, unsigned short* __restrict__ kws,
    float* __restrict__ wws) {
    __shared__ unsigned short Bb[2][NCOLS_PAD * BSTRIDE];
    __shared__ unsigned short Ab[2][1024];
    int t = threadIdx.x;
    int wave = t >> 6, lane = t & 63;
    int lr = lane & 15, kg = lane >> 4;
    int r0 = blockIdx.x * 16;

    int akk = t >> 7, alane = (t & 127) >> 1, ahalf = t & 1;
    int rowA = r0 + (alane & 15);
    int tA = rowA & (T_SEQ - 1), bA = rowA >> 12;
    const float* xrowA = x + ((size_t)tA * NBATCH + bA) * DM;

    bf16x8 breg[6];
    f32x4  areg;

    auto STAGE_LOAD = [&](int c) {
        int k0 = c * KC;
        #pragma unroll
        for (int it = 0; it < 6; ++it) {
            int tau = it * 256 + t;
            int col = tau >> 3, jg = tau & 7;
            breg[it] = *(const bf16x8*)(WT + (size_t)col * DM + k0 + jg * 8);
        }
        areg = *(const f32x4*)(xrowA + k0 + akk * 32 + (alane >> 4) * 8 + ahalf * 4);
    };
    auto STAGE_WRITE = [&](int buf) {
        #pragma unroll
        for (int it = 0; it < 6; ++it) {
            int tau = it * 256 + t;
            int col = tau >> 3, jg = tau & 7;
            *(bf16x8*)(&Bb[buf][col * BSTRIDE + jg * 8]) = breg[it];
        }
        unsigned short* d = &Ab[buf][akk * 512 + alane * 8 + ahalf * 4];
        d[0] = f2bf(areg[0]); d[1] = f2bf(areg[1]);
        d[2] = f2bf(areg[2]); d[3] = f2bf(areg[3]);
    };

    STAGE_LOAD(0);
    STAGE_WRITE(0);
    __syncthreads();

    int ct0 = wave * 3;
    f32x4 acc[3] = {};
    for (int c = 0; c < 16; ++c) {
        int buf = c & 1;
        if (c < 15) STAGE_LOAD(c + 1);
        #pragma unroll
        for (int kk = 0; kk < 2; ++kk) {
            bf16x8 af = *(const bf16x8*)(&Ab[buf][kk * 512 + lane * 8]);
            #pragma unroll
            for (int i = 0; i < 3; ++i) {
                int col = (ct0 + i) * 16 + lr;
                bf16x8 bfg = *(const bf16x8*)(&Bb[buf][col * BSTRIDE + kk * 32 + kg * 8]);
                acc[i] = __builtin_amdgcn_mfma_f32_16x16x32_bf16(af, bfg, acc[i], 0, 0, 0);
            }
        }
        if (c < 15) STAGE_WRITE(buf ^ 1);
        __syncthreads();
    }

    #pragma unroll
    for (int i = 0; i < 3; ++i) {
        int cout = (ct0 + i) * 16 + lr;
        float bv = bias[cout];
        #pragma unroll
        for (int r = 0; r < 4; ++r) {
            int rr = r0 + kg * 4 + r;
            int tt = rr & (T_SEQ - 1), bb = rr >> 12;
            float v = acc[i][r] + bv;
            size_t rowoff = (size_t)bb * T_SEQ + tt;
            if (cout < 128)       qws[rowoff * 128 + cout] = f2bf(v);
            else if (cout < 160)  kws[rowoff * 32 + (cout - 128)] = f2bf(v);
            else if (cout < 164)  wws[rowoff * 4 + (cout - 160)] = v;
        }
    }
}

// ---------------- indexer (R4 structure) x3 internal reps: rocprof probe ----------------
// Identical values rewritten 3x; pointers laundered per rep to defeat CSE.
// One ~97us dispatch -> surfaces in rocprof top-5 with full counters.
__global__ __launch_bounds__(256) void indexer_kernel(
    const unsigned short* __restrict__ qws, const unsigned short* __restrict__ kws,
    const float* __restrict__ wws, float* __restrict__ out) {
    int wave = threadIdx.x >> 6;
    int lane = threadIdx.x & 63;
    int gw = blockIdx.x * 4 + wave;        // 0..8191
    int strip = gw & 15;
    int t16 = (gw >> 4) & 255;
    int b = gw >> 12;
    int t0 = t16 * 16;
    int lr = lane & 15, kg = lane >> 4;

    const unsigned short* qrow = qws + ((size_t)b * T_SEQ + t0 + lr) * 128;
    bf16x8 qf[4];
    #pragma unroll
    for (int h = 0; h < 4; ++h)
        qf[h] = *(const bf16x8*)(qrow + h * 32 + kg * 8);

    f32x4 w4 = *(const f32x4*)(wws + ((size_t)b * T_SEQ + t0 + lr) * 4);

    float* outrow0 = out + (size_t)b * T_SEQ * T_SEQ + (size_t)(t0 + lr) * T_SEQ;
    const unsigned short* kbase0 = kws + (size_t)b * T_SEQ * 32;
    int sbase = strip * 256;

    for (int rep = 0; rep < 3; ++rep) {
        const unsigned short* kbase = kbase0;
        float* outrow = outrow0;
        asm volatile("" : "+v"(kbase));    // opaque: forces real reloads per rep
        asm volatile("" : "+v"(outrow));

        for (int g = 0; g < 4; ++g) {
            int s0 = sbase + g * 64;
            bf16x8 kf0 = *(const bf16x8*)(kbase + (size_t)(s0      + lr) * 32 + kg * 8);
            bf16x8 kf1 = *(const bf16x8*)(kbase + (size_t)(s0 + 16 + lr) * 32 + kg * 8);
            bf16x8 kf2 = *(const bf16x8*)(kbase + (size_t)(s0 + 32 + lr) * 32 + kg * 8);
            bf16x8 kf3 = *(const bf16x8*)(kbase + (size_t)(s0 + 48 + lr) * 32 + kg * 8);
            f32x4 z = {0.f, 0.f, 0.f, 0.f};
            f32x4 v[4];
            #pragma unroll
            for (int j = 0; j < 4; ++j) {
                bf16x8 kf = (j == 0) ? kf0 : (j == 1) ? kf1 : (j == 2) ? kf2 : kf3;
                f32x4 a0 = __builtin_amdgcn_mfma_f32_16x16x32_bf16(kf, qf[0], z, 0, 0, 0);
                f32x4 a1 = __builtin_amdgcn_mfma_f32_16x16x32_bf16(kf, qf[1], z, 0, 0, 0);
                f32x4 a2 = __builtin_amdgcn_mfma_f32_16x16x32_bf16(kf, qf[2], z, 0, 0, 0);
                f32x4 a3 = __builtin_amdgcn_mfma_f32_16x16x32_bf16(kf, qf[3], z, 0, 0, 0);
                #pragma unroll
                for (int r = 0; r < 4; ++r) {
                    v[j][r] = fmaxf(a0[r], 0.f) * w4[0] + fmaxf(a1[r], 0.f) * w4[1]
                            + fmaxf(a2[r], 0.f) * w4[2] + fmaxf(a3[r], 0.f) * w4[3];
                }
            }
            #pragma unroll
            for (int j = 0; j < 4; ++j)
                *(f32x4*)(outrow + s0 + j * 16 + kg * 4) = v[j];
        }
    }
}

extern "C" void kernel_launch(void* const* d_in, const int* in_sizes, int n_in,
                              void* d_out, int out_size, void* d_ws, size_t ws_size,
                              hipStream_t stream) {
    const float* x  = (const float*)d_in[0];
    const float* Wq = (const float*)d_in[1];
    const float* bq = (const float*)d_in[2];
    const float* Wk = (const float*)d_in[3];
    const float* bk = (const float*)d_in[4];
    const float* Ww = (const float*)d_in[5];
    const float* bw = (const float*)d_in[6];
    float* out = (float*)d_out;

    char* ws = (char*)d_ws;
    unsigned short* WT  = (unsigned short*)(ws);            // 192*1024*2 = 393216 B
    float* bias         = (float*)(ws + 393216);            // 768 B
    unsigned short* qws = (unsigned short*)(ws + 524288);   // 2 MB
    unsigned short* kws = (unsigned short*)(ws + 2621440);  // 512 KB
    float* wws          = (float*)(ws + 3145728);           // 128 KB

    prep_kernel<<<dim3(NCOLS_PAD), dim3(256), 0, stream>>>(Wq, bq, Wk, bk, Ww, bw, WT, bias);
    proj_kernel<<<dim3(512), dim3(256), 0, stream>>>(x, WT, bias, qws, kws, wws);
    indexer_kernel<<<dim3(2048), dim3(256), 0, stream>>>(qws, kws, wws, out);
}

// Round 13
// 58.978 us; speedup vs baseline: 1.6772x; 1.6772x over previous
//
#include <hip/hip_runtime.h>

#define T_SEQ 4096
#define NBATCH 2
#define DM 1024
#define DI 32
#define NH 4
#define NCOLS 164      // 128 q + 32 k + 4 w
#define NCOLS_PAD 192  // 12 tiles of 16
#define KC 64          // K-chunk
#define BSTRIDE 72     // shorts per col-slice in LDS (64 + 8 pad)

typedef __attribute__((ext_vector_type(8))) short bf16x8;
typedef __attribute__((ext_vector_type(4))) float f32x4;

__device__ __forceinline__ unsigned short f2bf(float f) {
    unsigned int u = __builtin_bit_cast(unsigned int, f);
    u += 0x7FFFu + ((u >> 16) & 1u);   // RNE; inputs have no NaN
    return (unsigned short)(u >> 16);
}

// ---------------- prep: W^T -> bf16 WT2[chunk][192 cols][64 k], bias[192] ----------------
// Fragment-major: proj's staging loads become fully contiguous 4-8 KB bursts.
__global__ __launch_bounds__(256) void prep_kernel(
    const float* __restrict__ Wq, const float* __restrict__ bq,
    const float* __restrict__ Wk, const float* __restrict__ bk,
    const float* __restrict__ Ww, const float* __restrict__ bw,
    unsigned short* __restrict__ WT2, float* __restrict__ bias) {
    int c = blockIdx.x;                    // col 0..191
    const float* src = nullptr; int stride = 0; float bv = 0.f;
    if (c < 128)      { src = Wq + c;       stride = NH * DI; bv = bq[c]; }
    else if (c < 160) { src = Wk + (c-128); stride = DI;      bv = bk[c-128]; }
    else if (c < 164) { src = Ww + (c-160); stride = NH;      bv = bw[c-160]; }
    for (int k = threadIdx.x; k < DM; k += blockDim.x) {
        float v = src ? src[(size_t)k * stride] : 0.f;
        WT2[((size_t)(k >> 6) * NCOLS_PAD + c) * KC + (k & 63)] = f2bf(v);
    }
    if (threadIdx.x == 0) bias[c] = bv;
}

// ---------------- projection v3: BM=32, 512 threads, LDS double-buffered ----------------
// 256 blocks (1/CU, 8 waves = 2/SIMD). WT2 restage: 256 x 384 KB = 98 MB L2
// (halved vs R9). Wave w: row-half rh=w&1, col-tiles ct0=(w>>1)*3. Per chunk:
// stage B (contiguous 12 KB) + A (8 KB) via issue-early/write-late; 2 A-reads
// + 6 B-reads (ds_read_b128, 2-way-free banks) + 6 MFMA; one barrier.
__global__ __launch_bounds__(512) void proj_kernel(
    const float* __restrict__ x, const unsigned short* __restrict__ WT2,
    const float* __restrict__ bias,
    unsigned short* __restrict__ qws, unsigned short* __restrict__ kws,
    float* __restrict__ wws) {
    __shared__ unsigned short Bb[2][NCOLS_PAD * BSTRIDE];  // 2 x 27648 B
    __shared__ unsigned short Ab[2][2048];                 // 2 x 4096 B
    int t = threadIdx.x;
    int wave = t >> 6, lane = t & 63;
    int lr = lane & 15, kg = lane >> 4;
    int r0 = blockIdx.x * 32;

    // A-staging map: thread -> 4 floats of the 32-row fragment layout
    int ahalf = t & 1, alane = (t >> 1) & 63, akk = (t >> 7) & 1, arh = t >> 8;
    int arow = r0 + arh * 16 + (alane & 15);
    int tA = arow & (T_SEQ - 1), bA = arow >> 12;
    const float* xrowA = x + ((size_t)tA * NBATCH + bA) * DM;
    int aoff = akk * 32 + (alane >> 4) * 8 + ahalf * 4;    // k-offset in chunk
    int adst = arh * 1024 + akk * 512 + alane * 8 + ahalf * 4;

    bf16x8 breg[3];
    f32x4  areg;

    auto STAGE_LOAD = [&](int c) {
        const unsigned short* wp = WT2 + (size_t)c * (NCOLS_PAD * KC);
        #pragma unroll
        for (int it = 0; it < 3; ++it) {
            int tau = it * 512 + t;
            breg[it] = *(const bf16x8*)(wp + tau * 8);     // contiguous
        }
        areg = *(const f32x4*)(xrowA + c * KC + aoff);
    };
    auto STAGE_WRITE = [&](int buf) {
        #pragma unroll
        for (int it = 0; it < 3; ++it) {
            int tau = it * 512 + t;
            int col = tau >> 3, jg = tau & 7;
            *(bf16x8*)(&Bb[buf][col * BSTRIDE + jg * 8]) = breg[it];
        }
        unsigned short* d = &Ab[buf][adst];
        d[0] = f2bf(areg[0]); d[1] = f2bf(areg[1]);
        d[2] = f2bf(areg[2]); d[3] = f2bf(areg[3]);
    };

    STAGE_LOAD(0);
    STAGE_WRITE(0);
    __syncthreads();

    int ct0 = (wave >> 1) * 3;             // 0,3,6,9 per wave-pair
    int rh  = wave & 1;                    // row-half
    f32x4 acc[3] = {};
    for (int c = 0; c < 16; ++c) {
        int buf = c & 1;
        if (c < 15) STAGE_LOAD(c + 1);
        #pragma unroll
        for (int kk = 0; kk < 2; ++kk) {
            bf16x8 af = *(const bf16x8*)(&Ab[buf][rh * 1024 + kk * 512 + lane * 8]);
            #pragma unroll
            for (int i = 0; i < 3; ++i) {
                int col = (ct0 + i) * 16 + lr;
                bf16x8 bfg = *(const bf16x8*)(&Bb[buf][col * BSTRIDE + kk * 32 + kg * 8]);
                acc[i] = __builtin_amdgcn_mfma_f32_16x16x32_bf16(af, bfg, acc[i], 0, 0, 0);
            }
        }
        if (c < 15) STAGE_WRITE(buf ^ 1);
        __syncthreads();
    }

    // epilogue: D col = lane&15, row = (lane>>4)*4 + reg (+ rh*16)
    #pragma unroll
    for (int i = 0; i < 3; ++i) {
        int cout = (ct0 + i) * 16 + lr;
        float bv = bias[cout];
        #pragma unroll
        for (int r = 0; r < 4; ++r) {
            int rr = r0 + rh * 16 + kg * 4 + r;
            int tt = rr & (T_SEQ - 1), bb = rr >> 12;
            float v = acc[i][r] + bv;
            size_t rowoff = (size_t)bb * T_SEQ + tt;
            if (cout < 128)       qws[rowoff * 128 + cout] = f2bf(v);
            else if (cout < 160)  kws[rowoff * 32 + (cout - 128)] = f2bf(v);
            else if (cout < 164)  wws[rowoff * 4 + (cout - 160)] = v;
        }
    }
}

// ---------------- main: out[b][t][s] = sum_h relu(q_h . k) * w_h ----------------
// (bit-identical to R9's best indexer: warm 27.6 us + ~5 us ramp)
__global__ __launch_bounds__(256) void indexer_kernel(
    const unsigned short* __restrict__ qws, const unsigned short* __restrict__ kws,
    const float* __restrict__ wws, float* __restrict__ out) {
    int wave = threadIdx.x >> 6;
    int lane = threadIdx.x & 63;
    int gw = blockIdx.x * 4 + wave;        // 0..8191
    int strip = gw & 15;
    int t16 = (gw >> 4) & 255;
    int b = gw >> 12;
    int t0 = t16 * 16;
    int lr = lane & 15, kg = lane >> 4;

    const unsigned short* qrow = qws + ((size_t)b * T_SEQ + t0 + lr) * 128;
    bf16x8 qf[4];
    #pragma unroll
    for (int h = 0; h < 4; ++h)
        qf[h] = *(const bf16x8*)(qrow + h * 32 + kg * 8);

    f32x4 w4 = *(const f32x4*)(wws + ((size_t)b * T_SEQ + t0 + lr) * 4);

    float* outrow = out + (size_t)b * T_SEQ * T_SEQ + (size_t)(t0 + lr) * T_SEQ;
    const unsigned short* kbase = kws + (size_t)b * T_SEQ * 32;
    int sbase = strip * 256;

    for (int g = 0; g < 4; ++g) {
        int s0 = sbase + g * 64;
        bf16x8 kf0 = *(const bf16x8*)(kbase + (size_t)(s0      + lr) * 32 + kg * 8);
        bf16x8 kf1 = *(const bf16x8*)(kbase + (size_t)(s0 + 16 + lr) * 32 + kg * 8);
        bf16x8 kf2 = *(const bf16x8*)(kbase + (size_t)(s0 + 32 + lr) * 32 + kg * 8);
        bf16x8 kf3 = *(const bf16x8*)(kbase + (size_t)(s0 + 48 + lr) * 32 + kg * 8);
        f32x4 z = {0.f, 0.f, 0.f, 0.f};
        f32x4 v[4];
        #pragma unroll
        for (int j = 0; j < 4; ++j) {
            bf16x8 kf = (j == 0) ? kf0 : (j == 1) ? kf1 : (j == 2) ? kf2 : kf3;
            f32x4 a0 = __builtin_amdgcn_mfma_f32_16x16x32_bf16(kf, qf[0], z, 0, 0, 0);
            f32x4 a1 = __builtin_amdgcn_mfma_f32_16x16x32_bf16(kf, qf[1], z, 0, 0, 0);
            f32x4 a2 = __builtin_amdgcn_mfma_f32_16x16x32_bf16(kf, qf[2], z, 0, 0, 0);
            f32x4 a3 = __builtin_amdgcn_mfma_f32_16x16x32_bf16(kf, qf[3], z, 0, 0, 0);
            #pragma unroll
            for (int r = 0; r < 4; ++r) {
                v[j][r] = fmaxf(a0[r], 0.f) * w4[0] + fmaxf(a1[r], 0.f) * w4[1]
                        + fmaxf(a2[r], 0.f) * w4[2] + fmaxf(a3[r], 0.f) * w4[3];
            }
        }
        #pragma unroll
        for (int j = 0; j < 4; ++j)
            *(f32x4*)(outrow + s0 + j * 16 + kg * 4) = v[j];
    }
}

extern "C" void kernel_launch(void* const* d_in, const int* in_sizes, int n_in,
                              void* d_out, int out_size, void* d_ws, size_t ws_size,
                              hipStream_t stream) {
    const float* x  = (const float*)d_in[0];
    const float* Wq = (const float*)d_in[1];
    const float* bq = (const float*)d_in[2];
    const float* Wk = (const float*)d_in[3];
    const float* bk = (const float*)d_in[4];
    const float* Ww = (const float*)d_in[5];
    const float* bw = (const float*)d_in[6];
    float* out = (float*)d_out;

    char* ws = (char*)d_ws;
    unsigned short* WT2 = (unsigned short*)(ws);            // 16*192*64*2 = 393216 B
    float* bias         = (float*)(ws + 393216);            // 768 B
    unsigned short* qws = (unsigned short*)(ws + 524288);   // 2 MB
    unsigned short* kws = (unsigned short*)(ws + 2621440);  // 512 KB
    float* wws          = (float*)(ws + 3145728);           // 128 KB

    prep_kernel<<<dim3(NCOLS_PAD), dim3(256), 0, stream>>>(Wq, bq, Wk, bk, Ww, bw, WT2, bias);
    proj_kernel<<<dim3(256), dim3(512), 0, stream>>>(x, WT2, bias, qws, kws, wws);
    indexer_kernel<<<dim3(2048), dim3(256), 0, stream>>>(qws, kws, wws, out);
}

// Round 14
// 54.149 us; speedup vs baseline: 1.8267x; 1.0892x over previous
//
#include <hip/hip_runtime.h>

#define T_SEQ 4096
#define NBATCH 2
#define DM 1024
#define DI 32
#define NH 4
#define NCOLS 164      // 128 q + 32 k + 4 w
#define NCOLS_PAD 192  // 12 tiles of 16
#define KC 64          // K-chunk
#define BSTRIDE 72     // shorts per col-slice in LDS (64 + 8 pad)

typedef __attribute__((ext_vector_type(8))) short bf16x8;
typedef __attribute__((ext_vector_type(4))) float f32x4;

__device__ __forceinline__ unsigned short f2bf(float f) {
    unsigned int u = __builtin_bit_cast(unsigned int, f);
    u += 0x7FFFu + ((u >> 16) & 1u);   // RNE; inputs have no NaN
    return (unsigned short)(u >> 16);
}

// ---------------- prep: W^T -> bf16 WT2[chunk][192 cols][64 k], bias[192] ----------------
__global__ __launch_bounds__(256) void prep_kernel(
    const float* __restrict__ Wq, const float* __restrict__ bq,
    const float* __restrict__ Wk, const float* __restrict__ bk,
    const float* __restrict__ Ww, const float* __restrict__ bw,
    unsigned short* __restrict__ WT2, float* __restrict__ bias) {
    int c = blockIdx.x;                    // col 0..191
    const float* src = nullptr; int stride = 0; float bv = 0.f;
    if (c < 128)      { src = Wq + c;       stride = NH * DI; bv = bq[c]; }
    else if (c < 160) { src = Wk + (c-128); stride = DI;      bv = bk[c-128]; }
    else if (c < 164) { src = Ww + (c-160); stride = NH;      bv = bw[c-160]; }
    for (int k = threadIdx.x; k < DM; k += blockDim.x) {
        float v = src ? src[(size_t)k * stride] : 0.f;
        WT2[((size_t)(k >> 6) * NCOLS_PAD + c) * KC + (k & 63)] = f2bf(v);
    }
    if (threadIdx.x == 0) bias[c] = bv;
}

// ---------------- projection v4: 2-deep register prefetch ----------------
// BM=32, 512 threads, 2 LDS buffers. Loads for chunk c+2 issued BEFORE the
// compute of chunk c -> ~500-700 cyc in flight (matches HBM latency) instead
// of R13's 1-phase (~200 cyc). Named A/B register sets (rule #20).
__global__ __launch_bounds__(512) void proj_kernel(
    const float* __restrict__ x, const unsigned short* __restrict__ WT2,
    const float* __restrict__ bias,
    unsigned short* __restrict__ qws, unsigned short* __restrict__ kws,
    float* __restrict__ wws) {
    __shared__ unsigned short Bb[2][NCOLS_PAD * BSTRIDE];  // 2 x 27648 B
    __shared__ unsigned short Ab[2][2048];                 // 2 x 4096 B
    int t = threadIdx.x;
    int wave = t >> 6, lane = t & 63;
    int lr = lane & 15, kg = lane >> 4;
    int r0 = blockIdx.x * 32;

    // A-staging map: thread -> 4 floats of the 32-row fragment layout
    int ahalf = t & 1, alane = (t >> 1) & 63, akk = (t >> 7) & 1, arh = t >> 8;
    int arow = r0 + arh * 16 + (alane & 15);
    int tA = arow & (T_SEQ - 1), bA = arow >> 12;
    const float* xrowA = x + ((size_t)tA * NBATCH + bA) * DM;
    int aoff = akk * 32 + (alane >> 4) * 8 + ahalf * 4;
    int adst = arh * 1024 + akk * 512 + alane * 8 + ahalf * 4;

    bf16x8 bregA[3], bregB[3];
    f32x4  aregA, aregB;

    auto LOADA = [&](int c) {
        const unsigned short* wp = WT2 + (size_t)c * (NCOLS_PAD * KC);
        #pragma unroll
        for (int it = 0; it < 3; ++it)
            bregA[it] = *(const bf16x8*)(wp + (it * 512 + t) * 8);
        aregA = *(const f32x4*)(xrowA + c * KC + aoff);
    };
    auto LOADB = [&](int c) {
        const unsigned short* wp = WT2 + (size_t)c * (NCOLS_PAD * KC);
        #pragma unroll
        for (int it = 0; it < 3; ++it)
            bregB[it] = *(const bf16x8*)(wp + (it * 512 + t) * 8);
        aregB = *(const f32x4*)(xrowA + c * KC + aoff);
    };
    auto WRITEA = [&](int buf) {
        #pragma unroll
        for (int it = 0; it < 3; ++it) {
            int tau = it * 512 + t;
            *(bf16x8*)(&Bb[buf][(tau >> 3) * BSTRIDE + (tau & 7) * 8]) = bregA[it];
        }
        unsigned short* d = &Ab[buf][adst];
        d[0] = f2bf(aregA[0]); d[1] = f2bf(aregA[1]);
        d[2] = f2bf(aregA[2]); d[3] = f2bf(aregA[3]);
    };
    auto WRITEB = [&](int buf) {
        #pragma unroll
        for (int it = 0; it < 3; ++it) {
            int tau = it * 512 + t;
            *(bf16x8*)(&Bb[buf][(tau >> 3) * BSTRIDE + (tau & 7) * 8]) = bregB[it];
        }
        unsigned short* d = &Ab[buf][adst];
        d[0] = f2bf(aregB[0]); d[1] = f2bf(aregB[1]);
        d[2] = f2bf(aregB[2]); d[3] = f2bf(aregB[3]);
    };

    int ct0 = (wave >> 1) * 3;
    int rh  = wave & 1;
    f32x4 acc[3] = {};

    auto COMPUTE = [&](int buf) {
        #pragma unroll
        for (int kk = 0; kk < 2; ++kk) {
            bf16x8 af = *(const bf16x8*)(&Ab[buf][rh * 1024 + kk * 512 + lane * 8]);
            #pragma unroll
            for (int i = 0; i < 3; ++i) {
                int col = (ct0 + i) * 16 + lr;
                bf16x8 bfg = *(const bf16x8*)(&Bb[buf][col * BSTRIDE + kk * 32 + kg * 8]);
                acc[i] = __builtin_amdgcn_mfma_f32_16x16x32_bf16(af, bfg, acc[i], 0, 0, 0);
            }
        }
    };

    // prologue: chunk0 -> buf0 (set A); chunk1 loaded (set B)
    LOADA(0);
    WRITEA(0);
    LOADB(1);
    __syncthreads();

    // steady state, 2 chunks per iteration, 2-deep prefetch
    for (int c = 0; c < 16; c += 2) {
        if (c + 2 < 16) LOADA(c + 2);      // in flight across ~2 compute phases
        COMPUTE(0);                         // chunk c from buf0
        __syncthreads();
        WRITEB(1);                          // chunk c+1 -> buf1
        __syncthreads();
        if (c + 3 < 16) LOADB(c + 3);
        COMPUTE(1);                         // chunk c+1 from buf1
        __syncthreads();
        if (c + 2 < 16) WRITEA(0);          // chunk c+2 -> buf0
        __syncthreads();
    }

    // epilogue: D col = lane&15, row = (lane>>4)*4 + reg (+ rh*16)
    #pragma unroll
    for (int i = 0; i < 3; ++i) {
        int cout = (ct0 + i) * 16 + lr;
        float bv = bias[cout];
        #pragma unroll
        for (int r = 0; r < 4; ++r) {
            int rr = r0 + rh * 16 + kg * 4 + r;
            int tt = rr & (T_SEQ - 1), bb = rr >> 12;
            float v = acc[i][r] + bv;
            size_t rowoff = (size_t)bb * T_SEQ + tt;
            if (cout < 128)       qws[rowoff * 128 + cout] = f2bf(v);
            else if (cout < 160)  kws[rowoff * 32 + (cout - 128)] = f2bf(v);
            else if (cout < 164)  wws[rowoff * 4 + (cout - 160)] = v;
        }
    }
}

// ---------------- main: out[b][t][s] = sum_h relu(q_h . k) * w_h ----------------
// (bit-identical to R9/R13 best indexer)
__global__ __launch_bounds__(256) void indexer_kernel(
    const unsigned short* __restrict__ qws, const unsigned short* __restrict__ kws,
    const float* __restrict__ wws, float* __restrict__ out) {
    int wave = threadIdx.x >> 6;
    int lane = threadIdx.x & 63;
    int gw = blockIdx.x * 4 + wave;        // 0..8191
    int strip = gw & 15;
    int t16 = (gw >> 4) & 255;
    int b = gw >> 12;
    int t0 = t16 * 16;
    int lr = lane & 15, kg = lane >> 4;

    const unsigned short* qrow = qws + ((size_t)b * T_SEQ + t0 + lr) * 128;
    bf16x8 qf[4];
    #pragma unroll
    for (int h = 0; h < 4; ++h)
        qf[h] = *(const bf16x8*)(qrow + h * 32 + kg * 8);

    f32x4 w4 = *(const f32x4*)(wws + ((size_t)b * T_SEQ + t0 + lr) * 4);

    float* outrow = out + (size_t)b * T_SEQ * T_SEQ + (size_t)(t0 + lr) * T_SEQ;
    const unsigned short* kbase = kws + (size_t)b * T_SEQ * 32;
    int sbase = strip * 256;

    for (int g = 0; g < 4; ++g) {
        int s0 = sbase + g * 64;
        bf16x8 kf0 = *(const bf16x8*)(kbase + (size_t)(s0      + lr) * 32 + kg * 8);
        bf16x8 kf1 = *(const bf16x8*)(kbase + (size_t)(s0 + 16 + lr) * 32 + kg * 8);
        bf16x8 kf2 = *(const bf16x8*)(kbase + (size_t)(s0 + 32 + lr) * 32 + kg * 8);
        bf16x8 kf3 = *(const bf16x8*)(kbase + (size_t)(s0 + 48 + lr) * 32 + kg * 8);
        f32x4 z = {0.f, 0.f, 0.f, 0.f};
        f32x4 v[4];
        #pragma unroll
        for (int j = 0; j < 4; ++j) {
            bf16x8 kf = (j == 0) ? kf0 : (j == 1) ? kf1 : (j == 2) ? kf2 : kf3;
            f32x4 a0 = __builtin_amdgcn_mfma_f32_16x16x32_bf16(kf, qf[0], z, 0, 0, 0);
            f32x4 a1 = __builtin_amdgcn_mfma_f32_16x16x32_bf16(kf, qf[1], z, 0, 0, 0);
            f32x4 a2 = __builtin_amdgcn_mfma_f32_16x16x32_bf16(kf, qf[2], z, 0, 0, 0);
            f32x4 a3 = __builtin_amdgcn_mfma_f32_16x16x32_bf16(kf, qf[3], z, 0, 0, 0);
            #pragma unroll
            for (int r = 0; r < 4; ++r) {
                v[j][r] = fmaxf(a0[r], 0.f) * w4[0] + fmaxf(a1[r], 0.f) * w4[1]
                        + fmaxf(a2[r], 0.f) * w4[2] + fmaxf(a3[r], 0.f) * w4[3];
            }
        }
        #pragma unroll
        for (int j = 0; j < 4; ++j)
            *(f32x4*)(outrow + s0 + j * 16 + kg * 4) = v[j];
    }
}

extern "C" void kernel_launch(void* const* d_in, const int* in_sizes, int n_in,
                              void* d_out, int out_size, void* d_ws, size_t ws_size,
                              hipStream_t stream) {
    const float* x  = (const float*)d_in[0];
    const float* Wq = (const float*)d_in[1];
    const float* bq = (const float*)d_in[2];
    const float* Wk = (const float*)d_in[3];
    const float* bk = (const float*)d_in[4];
    const float* Ww = (const float*)d_in[5];
    const float* bw = (const float*)d_in[6];
    float* out = (float*)d_out;

    char* ws = (char*)d_ws;
    unsigned short* WT2 = (unsigned short*)(ws);            // 16*192*64*2 = 393216 B
    float* bias         = (float*)(ws + 393216);            // 768 B
    unsigned short* qws = (unsigned short*)(ws + 524288);   // 2 MB
    unsigned short* kws = (unsigned short*)(ws + 2621440);  // 512 KB
    float* wws          = (float*)(ws + 3145728);           // 128 KB

    prep_kernel<<<dim3(NCOLS_PAD), dim3(256), 0, stream>>>(Wq, bq, Wk, bk, Ww, bw, WT2, bias);
    proj_kernel<<<dim3(256), dim3(512), 0, stream>>>(x, WT2, bias, qws, kws, wws);
    indexer_kernel<<<dim3(2048), dim3(256), 0, stream>>>(qws, kws, wws, out);
}

// Round 15
// 48.511 us; speedup vs baseline: 2.0391x; 1.1162x over previous
//
#include <hip/hip_runtime.h>

#define T_SEQ 4096
#define NBATCH 2
#define DM 1024
#define DI 32
#define NH 4
#define NCOLS 164      // 128 q + 32 k + 4 w
#define NCOLS_PAD 192  // 12 tiles of 16
#define KC 64          // K-chunk
#define BSTRIDE 72     // shorts per col-slice in LDS (64 + 8 pad)

typedef __attribute__((ext_vector_type(8))) short bf16x8;
typedef __attribute__((ext_vector_type(4))) float f32x4;

__device__ __forceinline__ unsigned short f2bf(float f) {
    unsigned int u = __builtin_bit_cast(unsigned int, f);
    u += 0x7FFFu + ((u >> 16) & 1u);   // RNE; inputs have no NaN
    return (unsigned short)(u >> 16);
}

// ---------------- prep: W^T -> bf16 WT2[chunk][192 cols][64 k], bias[192] ----------------
// (bit-identical to R14)
__global__ __launch_bounds__(256) void prep_kernel(
    const float* __restrict__ Wq, const float* __restrict__ bq,
    const float* __restrict__ Wk, const float* __restrict__ bk,
    const float* __restrict__ Ww, const float* __restrict__ bw,
    unsigned short* __restrict__ WT2, float* __restrict__ bias) {
    int c = blockIdx.x;                    // col 0..191
    const float* src = nullptr; int stride = 0; float bv = 0.f;
    if (c < 128)      { src = Wq + c;       stride = NH * DI; bv = bq[c]; }
    else if (c < 160) { src = Wk + (c-128); stride = DI;      bv = bk[c-128]; }
    else if (c < 164) { src = Ww + (c-160); stride = NH;      bv = bw[c-160]; }
    for (int k = threadIdx.x; k < DM; k += blockDim.x) {
        float v = src ? src[(size_t)k * stride] : 0.f;
        WT2[((size_t)(k >> 6) * NCOLS_PAD + c) * KC + (k & 63)] = f2bf(v);
    }
    if (threadIdx.x == 0) bias[c] = bv;
}

// ---------------- projection v4: 2-deep register prefetch (R14, best) ----------------
__global__ __launch_bounds__(512) void proj_kernel(
    const float* __restrict__ x, const unsigned short* __restrict__ WT2,
    const float* __restrict__ bias,
    unsigned short* __restrict__ qws, unsigned short* __restrict__ kws,
    float* __restrict__ wws) {
    __shared__ unsigned short Bb[2][NCOLS_PAD * BSTRIDE];
    __shared__ unsigned short Ab[2][2048];
    int t = threadIdx.x;
    int wave = t >> 6, lane = t & 63;
    int lr = lane & 15, kg = lane >> 4;
    int r0 = blockIdx.x * 32;

    int ahalf = t & 1, alane = (t >> 1) & 63, akk = (t >> 7) & 1, arh = t >> 8;
    int arow = r0 + arh * 16 + (alane & 15);
    int tA = arow & (T_SEQ - 1), bA = arow >> 12;
    const float* xrowA = x + ((size_t)tA * NBATCH + bA) * DM;
    int aoff = akk * 32 + (alane >> 4) * 8 + ahalf * 4;
    int adst = arh * 1024 + akk * 512 + alane * 8 + ahalf * 4;

    bf16x8 bregA[3], bregB[3];
    f32x4  aregA, aregB;

    auto LOADA = [&](int c) {
        const unsigned short* wp = WT2 + (size_t)c * (NCOLS_PAD * KC);
        #pragma unroll
        for (int it = 0; it < 3; ++it)
            bregA[it] = *(const bf16x8*)(wp + (it * 512 + t) * 8);
        aregA = *(const f32x4*)(xrowA + c * KC + aoff);
    };
    auto LOADB = [&](int c) {
        const unsigned short* wp = WT2 + (size_t)c * (NCOLS_PAD * KC);
        #pragma unroll
        for (int it = 0; it < 3; ++it)
            bregB[it] = *(const bf16x8*)(wp + (it * 512 + t) * 8);
        aregB = *(const f32x4*)(xrowA + c * KC + aoff);
    };
    auto WRITEA = [&](int buf) {
        #pragma unroll
        for (int it = 0; it < 3; ++it) {
            int tau = it * 512 + t;
            *(bf16x8*)(&Bb[buf][(tau >> 3) * BSTRIDE + (tau & 7) * 8]) = bregA[it];
        }
        unsigned short* d = &Ab[buf][adst];
        d[0] = f2bf(aregA[0]); d[1] = f2bf(aregA[1]);
        d[2] = f2bf(aregA[2]); d[3] = f2bf(aregA[3]);
    };
    auto WRITEB = [&](int buf) {
        #pragma unroll
        for (int it = 0; it < 3; ++it) {
            int tau = it * 512 + t;
            *(bf16x8*)(&Bb[buf][(tau >> 3) * BSTRIDE + (tau & 7) * 8]) = bregB[it];
        }
        unsigned short* d = &Ab[buf][adst];
        d[0] = f2bf(aregB[0]); d[1] = f2bf(aregB[1]);
        d[2] = f2bf(aregB[2]); d[3] = f2bf(aregB[3]);
    };

    int ct0 = (wave >> 1) * 3;
    int rh  = wave & 1;
    f32x4 acc[3] = {};

    auto COMPUTE = [&](int buf) {
        #pragma unroll
        for (int kk = 0; kk < 2; ++kk) {
            bf16x8 af = *(const bf16x8*)(&Ab[buf][rh * 1024 + kk * 512 + lane * 8]);
            #pragma unroll
            for (int i = 0; i < 3; ++i) {
                int col = (ct0 + i) * 16 + lr;
                bf16x8 bfg = *(const bf16x8*)(&Bb[buf][col * BSTRIDE + kk * 32 + kg * 8]);
                acc[i] = __builtin_amdgcn_mfma_f32_16x16x32_bf16(af, bfg, acc[i], 0, 0, 0);
            }
        }
    };

    LOADA(0);
    WRITEA(0);
    LOADB(1);
    __syncthreads();

    for (int c = 0; c < 16; c += 2) {
        if (c + 2 < 16) LOADA(c + 2);
        COMPUTE(0);
        __syncthreads();
        WRITEB(1);
        __syncthreads();
        if (c + 3 < 16) LOADB(c + 3);
        COMPUTE(1);
        __syncthreads();
        if (c + 2 < 16) WRITEA(0);
        __syncthreads();
    }

    #pragma unroll
    for (int i = 0; i < 3; ++i) {
        int cout = (ct0 + i) * 16 + lr;
        float bv = bias[cout];
        #pragma unroll
        for (int r = 0; r < 4; ++r) {
            int rr = r0 + rh * 16 + kg * 4 + r;
            int tt = rr & (T_SEQ - 1), bb = rr >> 12;
            float v = acc[i][r] + bv;
            size_t rowoff = (size_t)bb * T_SEQ + tt;
            if (cout < 128)       qws[rowoff * 128 + cout] = f2bf(v);
            else if (cout < 160)  kws[rowoff * 32 + (cout - 128)] = f2bf(v);
            else if (cout < 164)  wws[rowoff * 4 + (cout - 160)] = v;
        }
    }
}

// ---------------- indexer v4: LDS-staged k slab ----------------
// Block = 512 thr (8 waves) covering (b, 32 t-rows, 512-s slab). k-slab
// (32 KB) staged ONCE to LDS in fragment-linear layout (permuted ds_write);
// per-tile kf = one conflict-free linear ds_read_b128. Cuts k L2-read
// traffic 4x (256->64 MB) and frees VMEM issue for the write stream.
// Wave w = (t-half h=w&1, s-quarter sq=w>>1); per row a block writes 512
// consecutive floats. Compute/store body identical to proven R4 pattern.
__global__ __launch_bounds__(512) void indexer_kernel(
    const unsigned short* __restrict__ qws, const unsigned short* __restrict__ kws,
    const float* __restrict__ wws, float* __restrict__ out) {
    __shared__ unsigned short kf_lds[16384];   // 32 tiles x 64 lanes x 8 bf16
    int t = threadIdx.x;
    int wave = t >> 6;
    int lane = t & 63;
    int lr = lane & 15, kg = lane >> 4;

    int blk = blockIdx.x;                  // 0..2047
    int b = blk >> 10;
    int rem = blk & 1023;
    int t32 = rem >> 3;                    // 0..127
    int sblk = rem & 7;                    // 0..7
    int t0 = t32 * 32;
    int s0 = sblk * 512;

    const unsigned short* kbase = kws + (size_t)b * T_SEQ * 32;

    // stage k slab: thread t owns s-row s0+t (64 B, coalesced reads),
    // scatters into fragment-linear tiles: tile sl = t>>4, in-tile row t&15.
    {
        const unsigned short* krow = kbase + (size_t)(s0 + t) * 32;
        int ldst = (t >> 4) * 512 + (t & 15) * 8;
        #pragma unroll
        for (int j = 0; j < 4; ++j) {
            bf16x8 kv = *(const bf16x8*)(krow + j * 8);
            *(bf16x8*)(&kf_lds[ldst + j * 128]) = kv;
        }
    }

    int h = wave & 1;                      // t-half
    int sq = wave >> 1;                    // s-quarter (0..3)
    int trow = t0 + h * 16;

    const unsigned short* qrow = qws + ((size_t)b * T_SEQ + trow + lr) * 128;
    bf16x8 qf[4];
    #pragma unroll
    for (int hh = 0; hh < 4; ++hh)
        qf[hh] = *(const bf16x8*)(qrow + hh * 32 + kg * 8);

    f32x4 w4 = *(const f32x4*)(wws + ((size_t)b * T_SEQ + trow + lr) * 4);

    float* outrow = out + (size_t)b * T_SEQ * T_SEQ + (size_t)(trow + lr) * T_SEQ
                  + s0 + sq * 128;

    __syncthreads();

    #pragma unroll 2
    for (int st = 0; st < 8; ++st) {
        int sl = sq * 8 + st;
        bf16x8 kf = *(const bf16x8*)(&kf_lds[sl * 512 + lane * 8]);
        f32x4 z = {0.f, 0.f, 0.f, 0.f};
        f32x4 a0 = __builtin_amdgcn_mfma_f32_16x16x32_bf16(kf, qf[0], z, 0, 0, 0);
        f32x4 a1 = __builtin_amdgcn_mfma_f32_16x16x32_bf16(kf, qf[1], z, 0, 0, 0);
        f32x4 a2 = __builtin_amdgcn_mfma_f32_16x16x32_bf16(kf, qf[2], z, 0, 0, 0);
        f32x4 a3 = __builtin_amdgcn_mfma_f32_16x16x32_bf16(kf, qf[3], z, 0, 0, 0);
        f32x4 v;
        #pragma unroll
        for (int r = 0; r < 4; ++r) {
            v[r] = fmaxf(a0[r], 0.f) * w4[0] + fmaxf(a1[r], 0.f) * w4[1]
                 + fmaxf(a2[r], 0.f) * w4[2] + fmaxf(a3[r], 0.f) * w4[3];
        }
        *(f32x4*)(outrow + st * 16 + kg * 4) = v;
    }
}

extern "C" void kernel_launch(void* const* d_in, const int* in_sizes, int n_in,
                              void* d_out, int out_size, void* d_ws, size_t ws_size,
                              hipStream_t stream) {
    const float* x  = (const float*)d_in[0];
    const float* Wq = (const float*)d_in[1];
    const float* bq = (const float*)d_in[2];
    const float* Wk = (const float*)d_in[3];
    const float* bk = (const float*)d_in[4];
    const float* Ww = (const float*)d_in[5];
    const float* bw = (const float*)d_in[6];
    float* out = (float*)d_out;

    char* ws = (char*)d_ws;
    unsigned short* WT2 = (unsigned short*)(ws);            // 16*192*64*2 = 393216 B
    float* bias         = (float*)(ws + 393216);            // 768 B
    unsigned short* qws = (unsigned short*)(ws + 524288);   // 2 MB
    unsigned short* kws = (unsigned short*)(ws + 2621440);  // 512 KB
    float* wws          = (float*)(ws + 3145728);           // 128 KB

    prep_kernel<<<dim3(NCOLS_PAD), dim3(256), 0, stream>>>(Wq, bq, Wk, bk, Ww, bw, WT2, bias);
    proj_kernel<<<dim3(256), dim3(512), 0, stream>>>(x, WT2, bias, qws, kws, wws);
    indexer_kernel<<<dim3(2048), dim3(512), 0, stream>>>(qws, kws, wws, out);
}

// Round 16
// 47.563 us; speedup vs baseline: 2.0797x; 1.0199x over previous
//
#include <hip/hip_runtime.h>

#define T_SEQ 4096
#define NBATCH 2
#define DM 1024
#define DI 32
#define NH 4
#define NCOLS 164      // 128 q + 32 k + 4 w
#define NCOLS_PAD 192  // 12 tiles of 16
#define KC 64          // K-chunk
#define BSTRIDE 72     // shorts per col-slice in LDS (64 + 8 pad)

typedef __attribute__((ext_vector_type(8))) short bf16x8;
typedef __attribute__((ext_vector_type(4))) float f32x4;

__device__ __forceinline__ unsigned short f2bf(float f) {
    unsigned int u = __builtin_bit_cast(unsigned int, f);
    u += 0x7FFFu + ((u >> 16) & 1u);   // RNE; inputs have no NaN
    return (unsigned short)(u >> 16);
}

// ---------------- prep: W^T -> bf16 WT2[chunk][192 cols][64 k], bias[192] ----------------
// (bit-identical to R15)
__global__ __launch_bounds__(256) void prep_kernel(
    const float* __restrict__ Wq, const float* __restrict__ bq,
    const float* __restrict__ Wk, const float* __restrict__ bk,
    const float* __restrict__ Ww, const float* __restrict__ bw,
    unsigned short* __restrict__ WT2, float* __restrict__ bias) {
    int c = blockIdx.x;                    // col 0..191
    const float* src = nullptr; int stride = 0; float bv = 0.f;
    if (c < 128)      { src = Wq + c;       stride = NH * DI; bv = bq[c]; }
    else if (c < 160) { src = Wk + (c-128); stride = DI;      bv = bk[c-128]; }
    else if (c < 164) { src = Ww + (c-160); stride = NH;      bv = bw[c-160]; }
    for (int k = threadIdx.x; k < DM; k += blockDim.x) {
        float v = src ? src[(size_t)k * stride] : 0.f;
        WT2[((size_t)(k >> 6) * NCOLS_PAD + c) * KC + (k & 63)] = f2bf(v);
    }
    if (threadIdx.x == 0) bias[c] = bv;
}

// ---------------- projection v5: triple-buffer, 1 barrier/chunk ----------------
// BM=32, 512 threads, 3 LDS buffers, 2-deep register prefetch (R14 depth).
// WRITE(chunk c+1) targets the buffer last computed at c-2 (>=1 barrier ago)
// -> the second per-chunk barrier of R14 is unnecessary: 16 barriers, not 32.
__global__ __launch_bounds__(512) void proj_kernel(
    const float* __restrict__ x, const unsigned short* __restrict__ WT2,
    const float* __restrict__ bias,
    unsigned short* __restrict__ qws, unsigned short* __restrict__ kws,
    float* __restrict__ wws) {
    __shared__ unsigned short Bb[3][NCOLS_PAD * BSTRIDE];  // 3 x 27648 B
    __shared__ unsigned short Ab[3][2048];                 // 3 x 4096 B
    int t = threadIdx.x;
    int wave = t >> 6, lane = t & 63;
    int lr = lane & 15, kg = lane >> 4;
    int r0 = blockIdx.x * 32;

    int ahalf = t & 1, alane = (t >> 1) & 63, akk = (t >> 7) & 1, arh = t >> 8;
    int arow = r0 + arh * 16 + (alane & 15);
    int tA = arow & (T_SEQ - 1), bA = arow >> 12;
    const float* xrowA = x + ((size_t)tA * NBATCH + bA) * DM;
    int aoff = akk * 32 + (alane >> 4) * 8 + ahalf * 4;
    int adst = arh * 1024 + akk * 512 + alane * 8 + ahalf * 4;

    bf16x8 bregA[3], bregB[3];
    f32x4  aregA, aregB;

    auto LOADA = [&](int c) {
        const unsigned short* wp = WT2 + (size_t)c * (NCOLS_PAD * KC);
        #pragma unroll
        for (int it = 0; it < 3; ++it)
            bregA[it] = *(const bf16x8*)(wp + (it * 512 + t) * 8);
        aregA = *(const f32x4*)(xrowA + c * KC + aoff);
    };
    auto LOADB = [&](int c) {
        const unsigned short* wp = WT2 + (size_t)c * (NCOLS_PAD * KC);
        #pragma unroll
        for (int it = 0; it < 3; ++it)
            bregB[it] = *(const bf16x8*)(wp + (it * 512 + t) * 8);
        aregB = *(const f32x4*)(xrowA + c * KC + aoff);
    };
    auto WRITEA = [&](int buf) {
        #pragma unroll
        for (int it = 0; it < 3; ++it) {
            int tau = it * 512 + t;
            *(bf16x8*)(&Bb[buf][(tau >> 3) * BSTRIDE + (tau & 7) * 8]) = bregA[it];
        }
        unsigned short* d = &Ab[buf][adst];
        d[0] = f2bf(aregA[0]); d[1] = f2bf(aregA[1]);
        d[2] = f2bf(aregA[2]); d[3] = f2bf(aregA[3]);
    };
    auto WRITEB = [&](int buf) {
        #pragma unroll
        for (int it = 0; it < 3; ++it) {
            int tau = it * 512 + t;
            *(bf16x8*)(&Bb[buf][(tau >> 3) * BSTRIDE + (tau & 7) * 8]) = bregB[it];
        }
        unsigned short* d = &Ab[buf][adst];
        d[0] = f2bf(aregB[0]); d[1] = f2bf(aregB[1]);
        d[2] = f2bf(aregB[2]); d[3] = f2bf(aregB[3]);
    };

    int ct0 = (wave >> 1) * 3;
    int rh  = wave & 1;
    f32x4 acc[3] = {};

    auto COMPUTE = [&](int buf) {
        #pragma unroll
        for (int kk = 0; kk < 2; ++kk) {
            bf16x8 af = *(const bf16x8*)(&Ab[buf][rh * 1024 + kk * 512 + lane * 8]);
            #pragma unroll
            for (int i = 0; i < 3; ++i) {
                int col = (ct0 + i) * 16 + lr;
                bf16x8 bfg = *(const bf16x8*)(&Bb[buf][col * BSTRIDE + kk * 32 + kg * 8]);
                acc[i] = __builtin_amdgcn_mfma_f32_16x16x32_bf16(af, bfg, acc[i], 0, 0, 0);
            }
        }
    };

    // prologue: chunk0 -> buf0 (regs A); chunk1 in regs B
    LOADA(0);
    WRITEA(0);
    LOADB(1);
    __syncthreads();

    // steady state: 2 chunks / iter, ONE barrier per chunk
    int bc = 0;                            // buffer of chunk c
    for (int c = 0; c < 16; c += 2) {
        int b1 = (bc + 1 == 3) ? 0 : bc + 1;   // buffer of chunk c+1
        int b2 = (b1 + 1 == 3) ? 0 : b1 + 1;   // buffer of chunk c+2
        if (c + 2 < 16) LOADA(c + 2);      // 2-deep prefetch in flight
        COMPUTE(bc);                        // chunk c
        WRITEB(b1);                         // chunk c+1 -> its buffer (safe: last
        __syncthreads();                    //   read at c-2, >=1 barrier ago)
        if (c + 3 < 16) LOADB(c + 3);
        COMPUTE(b1);                        // chunk c+1
        if (c + 2 < 16) WRITEA(b2);         // chunk c+2
        __syncthreads();
        bc = b2;
    }

    // epilogue: D col = lane&15, row = (lane>>4)*4 + reg (+ rh*16)
    #pragma unroll
    for (int i = 0; i < 3; ++i) {
        int cout = (ct0 + i) * 16 + lr;
        float bv = bias[cout];
        #pragma unroll
        for (int r = 0; r < 4; ++r) {
            int rr = r0 + rh * 16 + kg * 4 + r;
            int tt = rr & (T_SEQ - 1), bb = rr >> 12;
            float v = acc[i][r] + bv;
            size_t rowoff = (size_t)bb * T_SEQ + tt;
            if (cout < 128)       qws[rowoff * 128 + cout] = f2bf(v);
            else if (cout < 160)  kws[rowoff * 32 + (cout - 128)] = f2bf(v);
            else if (cout < 164)  wws[rowoff * 4 + (cout - 160)] = v;
        }
    }
}

// ---------------- indexer v4: LDS-staged k slab (bit-identical to R15) ----------------
__global__ __launch_bounds__(512) void indexer_kernel(
    const unsigned short* __restrict__ qws, const unsigned short* __restrict__ kws,
    const float* __restrict__ wws, float* __restrict__ out) {
    __shared__ unsigned short kf_lds[16384];   // 32 tiles x 64 lanes x 8 bf16
    int t = threadIdx.x;
    int wave = t >> 6;
    int lane = t & 63;
    int lr = lane & 15, kg = lane >> 4;

    int blk = blockIdx.x;                  // 0..2047
    int b = blk >> 10;
    int rem = blk & 1023;
    int t32 = rem >> 3;                    // 0..127
    int sblk = rem & 7;                    // 0..7
    int t0 = t32 * 32;
    int s0 = sblk * 512;

    const unsigned short* kbase = kws + (size_t)b * T_SEQ * 32;

    {
        const unsigned short* krow = kbase + (size_t)(s0 + t) * 32;
        int ldst = (t >> 4) * 512 + (t & 15) * 8;
        #pragma unroll
        for (int j = 0; j < 4; ++j) {
            bf16x8 kv = *(const bf16x8*)(krow + j * 8);
            *(bf16x8*)(&kf_lds[ldst + j * 128]) = kv;
        }
    }

    int h = wave & 1;                      // t-half
    int sq = wave >> 1;                    // s-quarter (0..3)
    int trow = t0 + h * 16;

    const unsigned short* qrow = qws + ((size_t)b * T_SEQ + trow + lr) * 128;
    bf16x8 qf[4];
    #pragma unroll
    for (int hh = 0; hh < 4; ++hh)
        qf[hh] = *(const bf16x8*)(qrow + hh * 32 + kg * 8);

    f32x4 w4 = *(const f32x4*)(wws + ((size_t)b * T_SEQ + trow + lr) * 4);

    float* outrow = out + (size_t)b * T_SEQ * T_SEQ + (size_t)(trow + lr) * T_SEQ
                  + s0 + sq * 128;

    __syncthreads();

    #pragma unroll 2
    for (int st = 0; st < 8; ++st) {
        int sl = sq * 8 + st;
        bf16x8 kf = *(const bf16x8*)(&kf_lds[sl * 512 + lane * 8]);
        f32x4 z = {0.f, 0.f, 0.f, 0.f};
        f32x4 a0 = __builtin_amdgcn_mfma_f32_16x16x32_bf16(kf, qf[0], z, 0, 0, 0);
        f32x4 a1 = __builtin_amdgcn_mfma_f32_16x16x32_bf16(kf, qf[1], z, 0, 0, 0);
        f32x4 a2 = __builtin_amdgcn_mfma_f32_16x16x32_bf16(kf, qf[2], z, 0, 0, 0);
        f32x4 a3 = __builtin_amdgcn_mfma_f32_16x16x32_bf16(kf, qf[3], z, 0, 0, 0);
        f32x4 v;
        #pragma unroll
        for (int r = 0; r < 4; ++r) {
            v[r] = fmaxf(a0[r], 0.f) * w4[0] + fmaxf(a1[r], 0.f) * w4[1]
                 + fmaxf(a2[r], 0.f) * w4[2] + fmaxf(a3[r], 0.f) * w4[3];
        }
        *(f32x4*)(outrow + st * 16 + kg * 4) = v;
    }
}

extern "C" void kernel_launch(void* const* d_in, const int* in_sizes, int n_in,
                              void* d_out, int out_size, void* d_ws, size_t ws_size,
                              hipStream_t stream) {
    const float* x  = (const float*)d_in[0];
    const float* Wq = (const float*)d_in[1];
    const float* bq = (const float*)d_in[2];
    const float* Wk = (const float*)d_in[3];
    const float* bk = (const float*)d_in[4];
    const float* Ww = (const float*)d_in[5];
    const float* bw = (const float*)d_in[6];
    float* out = (float*)d_out;

    char* ws = (char*)d_ws;
    unsigned short* WT2 = (unsigned short*)(ws);            // 16*192*64*2 = 393216 B
    float* bias         = (float*)(ws + 393216);            // 768 B
    unsigned short* qws = (unsigned short*)(ws + 524288);   // 2 MB
    unsigned short* kws = (unsigned short*)(ws + 2621440);  // 512 KB
    float* wws          = (float*)(ws + 3145728);           // 128 KB

    prep_kernel<<<dim3(NCOLS_PAD), dim3(256), 0, stream>>>(Wq, bq, Wk, bk, Ww, bw, WT2, bias);
    proj_kernel<<<dim3(256), dim3(512), 0, stream>>>(x, WT2, bias, qws, kws, wws);
    indexer_kernel<<<dim3(2048), dim3(512), 0, stream>>>(qws, kws, wws, out);
}